// Round 8
// baseline (56.075 us; speedup 1.0000x reference)
//
#include <hip/hip_runtime.h>
#include <math.h>

// Gaussian KDE, n=12000. 2 dispatches:
//   1) sel_k   1x1024: stats+min/max; EXACT Q25/Q75 order stats via value-linear
//      2048-bin histogram (near-conflict-free LDS atomics) + candidate-bin
//      rank-select; computes h; writes pre-scaled ejwj[]; zeroes column counters.
//   2) kdefin_k grid(47,16)x256: partial[y*nmax+i] = sum_{j in win} w'_j*exp2(-(e_i-e_j)^2);
//      last block of each ib-column (device atomic counter) sums its 16 window
//      partials in fixed order and writes out[i] = log(pdf + 1e-10).
// All float accumulation orders fixed; int atomics order-independent; the
// rank-select picks the kk-th smallest of a multiset (permutation-invariant)
// -> bit-deterministic across replays.

#define BLK 256
#define YW 16
#define MAXWIN 768
#define MAXN 12032
#define NB 2048
#define CAND 512

#if defined(__has_builtin)
#if __has_builtin(__builtin_amdgcn_exp2f)
#define EXP2(x) __builtin_amdgcn_exp2f(x)
#endif
#endif
#ifndef EXP2
#define EXP2(x) exp2f(x)
#endif

__global__ __launch_bounds__(1024) void sel_k(const float* __restrict__ d,
                                              const float* __restrict__ w,
                                              float2* __restrict__ ejwj,
                                              int* __restrict__ colcnt,
                                              int n, int nmax, int ncols) {
    __shared__ float sdata[MAXN];    // 48.1 KB
    __shared__ int hist[NB];         // 8 KB
    __shared__ int cum[NB];          // 8 KB
    __shared__ float cand[4][CAND];  // 8 KB
    __shared__ int ccnt[4];
    __shared__ int tb[4], tprev[4];
    __shared__ float4 sstat[16];
    __shared__ float2 smm[16];
    __shared__ int wtot[16];
    __shared__ float sq[4];
    __shared__ float sparams[2];
    __shared__ float slh[2];

    const int t = threadIdx.x, lane = t & 63, wid = t >> 6;

    for (int b = t; b < NB; b += 1024) hist[b] = 0;
    if (t < 4) ccnt[t] = 0;
    if (t < ncols) colcnt[t] = 0;          // reset kdefin column counters

    // ---- pass 1: stage d in LDS; stats + min/max partials ----
    float s1 = 0.f, s2 = 0.f, sd = 0.f, sd2 = 0.f;
    float mn = __int_as_float(0x7f800000), mx = __int_as_float(0xff800000);
    for (int i = t; i < n; i += 1024) {
        float dv = d[i], wv = w[i];
        sdata[i] = dv;
        s1 += wv; s2 += wv * wv; sd += dv; sd2 += dv * dv;
        mn = fminf(mn, dv); mx = fmaxf(mx, dv);
    }
    for (int off = 32; off > 0; off >>= 1) {
        s1 += __shfl_down(s1, off); s2 += __shfl_down(s2, off);
        sd += __shfl_down(sd, off); sd2 += __shfl_down(sd2, off);
        mn = fminf(mn, __shfl_down(mn, off));
        mx = fmaxf(mx, __shfl_down(mx, off));
    }
    if (lane == 0) { sstat[wid] = make_float4(s1, s2, sd, sd2); smm[wid] = make_float2(mn, mx); }
    __syncthreads();
    if (t == 0) {
        float lo = smm[0].x, hi = smm[0].y;
        for (int q = 1; q < 16; ++q) { lo = fminf(lo, smm[q].x); hi = fmaxf(hi, smm[q].y); }
        slh[0] = lo; slh[1] = hi;
    }
    __syncthreads();
    const float lo = slh[0];
    const float range = slh[1] - lo;
    const float scale = (range > 0.f) ? (float)NB / range : 0.f;

    // ---- pass 2: value-linear histogram (monotone binning -> exact ranks) ----
    for (int i = t; i < n; i += 1024) {
        int b = (int)((sdata[i] - lo) * scale);
        atomicAdd(&hist[b < NB ? b : NB - 1], 1);
    }
    __syncthreads();

    // ---- inclusive scan hist -> cum ----
    {
        const int b0 = t * 2;
        int a0 = hist[b0], a1 = hist[b0 + 1];
        int seg = a0 + a1, v = seg;
        for (int off = 1; off < 64; off <<= 1) {
            int u = __shfl_up(v, off);
            if (lane >= off) v += u;
        }
        if (lane == 63) wtot[wid] = v;
        __syncthreads();
        if (t == 0) {
            int acc = 0;
            for (int q = 0; q < 16; ++q) { int tmp = wtot[q]; wtot[q] = acc; acc += tmp; }
        }
        __syncthreads();
        int excl = wtot[wid] + (v - seg);
        cum[b0] = excl + a0;
        cum[b0 + 1] = excl + a0 + a1;
        __syncthreads();
    }

    // ---- locate target bins ----
    const double p25 = 0.25 * (double)(n - 1);
    const double p75 = 0.75 * (double)(n - 1);
    const int l25 = (int)p25, l75 = (int)p75;
    const int u25 = (l25 + 1 < n) ? l25 + 1 : l25;
    const int u75 = (l75 + 1 < n) ? l75 + 1 : l75;
    const int targets[4] = {l25, u25, l75, u75};
    for (int b = t; b < NB; b += 1024) {
        int incl = cum[b], prev = b ? cum[b - 1] : 0;
        #pragma unroll
        for (int r = 0; r < 4; ++r)
            if (prev <= targets[r] && targets[r] < incl) { tb[r] = b; tprev[r] = prev; }
    }
    __syncthreads();

    // ---- pass 3: collect candidates of the (<=4) target bins ----
    const int tb0 = tb[0], tb1 = tb[1], tb2 = tb[2], tb3 = tb[3];
    for (int i = t; i < n; i += 1024) {
        float dv = sdata[i];
        int b = (int)((dv - lo) * scale);
        b = b < NB ? b : NB - 1;
        if (b == tb0) { int p = atomicAdd(&ccnt[0], 1); if (p < CAND) cand[0][p] = dv; }
        if (b == tb1) { int p = atomicAdd(&ccnt[1], 1); if (p < CAND) cand[1][p] = dv; }
        if (b == tb2) { int p = atomicAdd(&ccnt[2], 1); if (p < CAND) cand[2][p] = dv; }
        if (b == tb3) { int p = atomicAdd(&ccnt[3], 1); if (p < CAND) cand[3][p] = dv; }
    }
    __syncthreads();

    // ---- exact rank-select within candidate arrays (wave r per target) ----
    if (wid < 4) {
        const int r = wid;
        const int kk = targets[r] - tprev[r];
        const int m = ccnt[r] < CAND ? ccnt[r] : CAND;
        for (int ci = lane; ci < m; ci += 64) {
            float v = cand[r][ci];
            int rk = 0;
            for (int j = 0; j < m; ++j) {
                float u = cand[r][j];
                rk += (u < v) || (u == v && j < ci);   // index tiebreak: distinct ranks
            }
            if (rk == kk) sq[r] = v;                    // kk-th smallest: perm-invariant
        }
    }
    __syncthreads();

    // ---- h + scales ----
    if (t == 0) {
        double S1 = 0, S2 = 0, Sd = 0, Sd2 = 0;
        for (int q = 0; q < 16; ++q) {
            float4 v = sstat[q];
            S1 += v.x; S2 += v.y; Sd += v.z; Sd2 += v.w;
        }
        double neff = S1 * S1 / S2;
        double var  = (Sd2 - Sd * Sd / (double)n) / ((double)n - 1.0);
        double sdev = sqrt(var);
        double f25 = p25 - (double)l25, f75 = p75 - (double)l75;
        double q25 = (double)sq[0] + f25 * ((double)sq[1] - (double)sq[0]);
        double q75 = (double)sq[2] + f75 * ((double)sq[3] - (double)sq[2]);
        double sig = fmin(sdev, (q75 - q25) / 1.34);
        double h = 0.9 * sig * pow(neff, -0.2);
        sparams[0] = (float)(sqrt(0.5 * 1.4426950408889634) / h);          // r
        sparams[1] = (float)(1.0 / (h * sqrt(6.283185307179586) * S1));    // wsc
    }
    __syncthreads();
    const float rr = sparams[0], wsc = sparams[1];
    for (int j = t; j < nmax; j += 1024)
        ejwj[j] = (j < n) ? make_float2(sdata[j] * rr, w[j] * wsc) : make_float2(0.f, 0.f);
}

__global__ __launch_bounds__(BLK) void kdefin_k(const float2* __restrict__ ejwj,
                                                float* __restrict__ partial,
                                                float* __restrict__ out,
                                                int* __restrict__ colcnt,
                                                int n, int nmax) {
    __shared__ float2 sj[MAXWIN];    // 6 KB
    __shared__ float sredf[1024];    // 4 KB
    __shared__ int slast;
    const int t = threadIdx.x, ib = blockIdx.x, y = blockIdx.y;
    const int lane = t & 63, wv = t >> 6;
    const int WIN = nmax / YW;       // 752
    const int j0 = y * WIN;

    for (int idx = t; idx < (WIN >> 1); idx += BLK)
        ((float4*)sj)[idx] = ((const float4*)(ejwj + j0))[idx];
    const int i0 = ib * 256 + lane;
    const float ei0 = ejwj[i0].x;
    const float ei1 = ejwj[i0 + 64].x;
    const float ei2 = ejwj[i0 + 128].x;
    const float ei3 = ejwj[i0 + 192].x;
    __syncthreads();

    float a0 = 0.f, a1 = 0.f, a2 = 0.f, a3 = 0.f;
    {
        const float4* pj = (const float4*)(sj + wv * (WIN >> 2));  // 188 float2/wave
        const int nq = WIN >> 3;  // 94 float4 = 188 j's
        for (int jj = 0; jj < nq; ++jj) {
            float4 q = pj[jj];  // (e_a, w_a, e_b, w_b)
            { float u = ei0 - q.x, v = ei0 - q.z;
              a0 = fmaf(q.y, EXP2(-(u * u)), a0); a0 = fmaf(q.w, EXP2(-(v * v)), a0); }
            { float u = ei1 - q.x, v = ei1 - q.z;
              a1 = fmaf(q.y, EXP2(-(u * u)), a1); a1 = fmaf(q.w, EXP2(-(v * v)), a1); }
            { float u = ei2 - q.x, v = ei2 - q.z;
              a2 = fmaf(q.y, EXP2(-(u * u)), a2); a2 = fmaf(q.w, EXP2(-(v * v)), a2); }
            { float u = ei3 - q.x, v = ei3 - q.z;
              a3 = fmaf(q.y, EXP2(-(u * u)), a3); a3 = fmaf(q.w, EXP2(-(v * v)), a3); }
        }
    }
    __syncthreads();
    sredf[wv * 256 +       lane] = a0;
    sredf[wv * 256 +  64 + lane] = a1;
    sredf[wv * 256 + 128 + lane] = a2;
    sredf[wv * 256 + 192 + lane] = a3;
    __syncthreads();
    partial[y * nmax + ib * 256 + t] =
        sredf[t] + sredf[256 + t] + sredf[512 + t] + sredf[768 + t];

    // scoped tail: 16th block of this ib-column finalizes its 256 i's
    if (t == 0) {
        __threadfence();                              // release partial write
        int old = atomicAdd(&colcnt[ib], 1);
        slast = (old == YW - 1) ? 1 : 0;
    }
    __syncthreads();
    if (slast) {
        __threadfence();                              // acquire others' partials
        int i = ib * 256 + t;
        float p = 0.f;
        #pragma unroll
        for (int y2 = 0; y2 < YW; ++y2) p += partial[y2 * nmax + i];
        if (i < n) out[i] = logf(p + 1e-10f);
    }
}

extern "C" void kernel_launch(void* const* d_in, const int* in_sizes, int n_in,
                              void* d_out, int out_size, void* d_ws, size_t ws_size,
                              hipStream_t stream) {
    const float* d = (const float*)d_in[0];
    const float* w = (const float*)d_in[1];
    float* out = (float*)d_out;
    const int n = in_sizes[0];

    const int nmax = ((n + 255) / 256) * 256;   // 12032
    const int IB = nmax / 256;                  // 47

    // ws layout (float units): ejwj float2[nmax] | partial float[YW*nmax] | colcnt int[IB]
    float*  wsf     = (float*)d_ws;
    float2* ejwj    = (float2*)wsf;
    float*  partial = wsf + 2 * nmax;
    int*    colcnt  = (int*)(wsf + 2 * nmax + YW * nmax);

    sel_k<<<1, 1024, 0, stream>>>(d, w, ejwj, colcnt, n, nmax, IB);
    dim3 grid(IB, YW);
    kdefin_k<<<grid, BLK, 0, stream>>>(ejwj, partial, out, colcnt, n, nmax);
}

// Round 9
// 41.542 us; speedup vs baseline: 1.3498x; 1.3498x over previous
//
#include <hip/hip_runtime.h>
#include <math.h>

// Gaussian KDE, n=12000. 3 dispatches (OV ~1.5us each):
//   1) sel_k 1x1024: stats+min/max; EXACT Q25/Q75 via value-linear 2048-bin
//      histogram + candidate rank-select; computes h; writes pre-scaled ejwj[].
//   2) kde_k grid(47,32)x256: II=4, j-window 376 -> 1504 blocks (~6 waves/SIMD)
//      partial[y*nmax+i] = sum_{j in win} w'_j * exp2(-(e_i-e_j)^2)
//   3) fin_k 47x256: out[i] = log(sum_{y<32} partial[y][i] + 1e-10)
// Fixed accumulation orders; int atomics order-independent -> bit-deterministic.

#define BLK 256
#define YWK 32
#define MAXWIN 384
#define MAXN 12032
#define NB 2048
#define CAND 512

#if defined(__has_builtin)
#if __has_builtin(__builtin_amdgcn_exp2f)
#define EXP2(x) __builtin_amdgcn_exp2f(x)
#endif
#endif
#ifndef EXP2
#define EXP2(x) exp2f(x)
#endif

__global__ __launch_bounds__(1024) void sel_k(const float* __restrict__ d,
                                              const float* __restrict__ w,
                                              float2* __restrict__ ejwj,
                                              int n, int nmax) {
    __shared__ float sdata[MAXN];    // 48.1 KB
    __shared__ int hist[NB];         // 8 KB
    __shared__ int cum[NB];          // 8 KB
    __shared__ float cand[4][CAND];  // 8 KB
    __shared__ int ccnt[4];
    __shared__ int tb[4], tprev[4];
    __shared__ float4 sstat[16];
    __shared__ float2 smm[16];
    __shared__ int wtot[16];
    __shared__ float sq[4];
    __shared__ float sparams[2];
    __shared__ float slh[2];

    const int t = threadIdx.x, lane = t & 63, wid = t >> 6;

    for (int b = t; b < NB; b += 1024) hist[b] = 0;
    if (t < 4) ccnt[t] = 0;

    // ---- pass 1: stage d in LDS; stats + min/max partials ----
    float s1 = 0.f, s2 = 0.f, sd = 0.f, sd2 = 0.f;
    float mn = __int_as_float(0x7f800000), mx = __int_as_float(0xff800000);
    for (int i = t; i < n; i += 1024) {
        float dv = d[i], wv = w[i];
        sdata[i] = dv;
        s1 += wv; s2 += wv * wv; sd += dv; sd2 += dv * dv;
        mn = fminf(mn, dv); mx = fmaxf(mx, dv);
    }
    for (int off = 32; off > 0; off >>= 1) {
        s1 += __shfl_down(s1, off); s2 += __shfl_down(s2, off);
        sd += __shfl_down(sd, off); sd2 += __shfl_down(sd2, off);
        mn = fminf(mn, __shfl_down(mn, off));
        mx = fmaxf(mx, __shfl_down(mx, off));
    }
    if (lane == 0) { sstat[wid] = make_float4(s1, s2, sd, sd2); smm[wid] = make_float2(mn, mx); }
    __syncthreads();
    if (t == 0) {
        float lo = smm[0].x, hi = smm[0].y;
        for (int q = 1; q < 16; ++q) { lo = fminf(lo, smm[q].x); hi = fmaxf(hi, smm[q].y); }
        slh[0] = lo; slh[1] = hi;
    }
    __syncthreads();
    const float lo = slh[0];
    const float range = slh[1] - lo;
    const float scale = (range > 0.f) ? (float)NB / range : 0.f;

    // ---- pass 2: value-linear histogram (monotone binning -> exact ranks) ----
    for (int i = t; i < n; i += 1024) {
        int b = (int)((sdata[i] - lo) * scale);
        atomicAdd(&hist[b < NB ? b : NB - 1], 1);
    }
    __syncthreads();

    // ---- inclusive scan hist -> cum ----
    {
        const int b0 = t * 2;
        int a0 = hist[b0], a1 = hist[b0 + 1];
        int seg = a0 + a1, v = seg;
        for (int off = 1; off < 64; off <<= 1) {
            int u = __shfl_up(v, off);
            if (lane >= off) v += u;
        }
        if (lane == 63) wtot[wid] = v;
        __syncthreads();
        if (t == 0) {
            int acc = 0;
            for (int q = 0; q < 16; ++q) { int tmp = wtot[q]; wtot[q] = acc; acc += tmp; }
        }
        __syncthreads();
        int excl = wtot[wid] + (v - seg);
        cum[b0] = excl + a0;
        cum[b0 + 1] = excl + a0 + a1;
        __syncthreads();
    }

    // ---- locate target bins ----
    const double p25 = 0.25 * (double)(n - 1);
    const double p75 = 0.75 * (double)(n - 1);
    const int l25 = (int)p25, l75 = (int)p75;
    const int u25 = (l25 + 1 < n) ? l25 + 1 : l25;
    const int u75 = (l75 + 1 < n) ? l75 + 1 : l75;
    const int targets[4] = {l25, u25, l75, u75};
    for (int b = t; b < NB; b += 1024) {
        int incl = cum[b], prev = b ? cum[b - 1] : 0;
        #pragma unroll
        for (int r = 0; r < 4; ++r)
            if (prev <= targets[r] && targets[r] < incl) { tb[r] = b; tprev[r] = prev; }
    }
    __syncthreads();

    // ---- pass 3: collect candidates of the (<=4) target bins ----
    const int tb0 = tb[0], tb1 = tb[1], tb2 = tb[2], tb3 = tb[3];
    for (int i = t; i < n; i += 1024) {
        float dv = sdata[i];
        int b = (int)((dv - lo) * scale);
        b = b < NB ? b : NB - 1;
        if (b == tb0) { int p = atomicAdd(&ccnt[0], 1); if (p < CAND) cand[0][p] = dv; }
        if (b == tb1) { int p = atomicAdd(&ccnt[1], 1); if (p < CAND) cand[1][p] = dv; }
        if (b == tb2) { int p = atomicAdd(&ccnt[2], 1); if (p < CAND) cand[2][p] = dv; }
        if (b == tb3) { int p = atomicAdd(&ccnt[3], 1); if (p < CAND) cand[3][p] = dv; }
    }
    __syncthreads();

    // ---- exact rank-select within candidate arrays (wave r per target) ----
    if (wid < 4) {
        const int r = wid;
        const int kk = targets[r] - tprev[r];
        const int m = ccnt[r] < CAND ? ccnt[r] : CAND;
        for (int ci = lane; ci < m; ci += 64) {
            float v = cand[r][ci];
            int rk = 0;
            for (int j = 0; j < m; ++j) {
                float u = cand[r][j];
                rk += (u < v) || (u == v && j < ci);   // index tiebreak: distinct ranks
            }
            if (rk == kk) sq[r] = v;                    // kk-th smallest: perm-invariant
        }
    }
    __syncthreads();

    // ---- h + scales ----
    if (t == 0) {
        double S1 = 0, S2 = 0, Sd = 0, Sd2 = 0;
        for (int q = 0; q < 16; ++q) {
            float4 v = sstat[q];
            S1 += v.x; S2 += v.y; Sd += v.z; Sd2 += v.w;
        }
        double neff = S1 * S1 / S2;
        double var  = (Sd2 - Sd * Sd / (double)n) / ((double)n - 1.0);
        double sdev = sqrt(var);
        double f25 = p25 - (double)l25, f75 = p75 - (double)l75;
        double q25 = (double)sq[0] + f25 * ((double)sq[1] - (double)sq[0]);
        double q75 = (double)sq[2] + f75 * ((double)sq[3] - (double)sq[2]);
        double sig = fmin(sdev, (q75 - q25) / 1.34);
        double h = 0.9 * sig * pow(neff, -0.2);
        sparams[0] = (float)(sqrt(0.5 * 1.4426950408889634) / h);          // r
        sparams[1] = (float)(1.0 / (h * sqrt(6.283185307179586) * S1));    // wsc
    }
    __syncthreads();
    const float rr = sparams[0], wsc = sparams[1];
    for (int j = t; j < nmax; j += 1024)
        ejwj[j] = (j < n) ? make_float2(sdata[j] * rr, w[j] * wsc) : make_float2(0.f, 0.f);
}

__global__ __launch_bounds__(BLK) void kde_k(const float2* __restrict__ ejwj,
                                             float* __restrict__ partial,
                                             int n, int nmax, int WIN) {
    __shared__ float2 sj[MAXWIN];    // 3 KB
    __shared__ float sredf[1024];    // 4 KB
    const int t = threadIdx.x, ib = blockIdx.x, y = blockIdx.y;
    const int lane = t & 63, wv = t >> 6;
    const int j0 = y * WIN;

    for (int idx = t; idx < (WIN >> 1); idx += BLK)
        ((float4*)sj)[idx] = ((const float4*)(ejwj + j0))[idx];
    const int i0 = ib * 256 + lane;
    const float ei0 = ejwj[i0].x;
    const float ei1 = ejwj[i0 + 64].x;
    const float ei2 = ejwj[i0 + 128].x;
    const float ei3 = ejwj[i0 + 192].x;
    __syncthreads();

    float a0 = 0.f, a1 = 0.f, a2 = 0.f, a3 = 0.f;
    {
        const float4* pj = (const float4*)(sj + wv * (WIN >> 2));  // 94 float2/wave
        const int nq = WIN >> 3;  // 47 float4 = 94 j's
        for (int jj = 0; jj < nq; ++jj) {
            float4 q = pj[jj];  // (e_a, w_a, e_b, w_b)
            { float u = ei0 - q.x, v = ei0 - q.z;
              a0 = fmaf(q.y, EXP2(-(u * u)), a0); a0 = fmaf(q.w, EXP2(-(v * v)), a0); }
            { float u = ei1 - q.x, v = ei1 - q.z;
              a1 = fmaf(q.y, EXP2(-(u * u)), a1); a1 = fmaf(q.w, EXP2(-(v * v)), a1); }
            { float u = ei2 - q.x, v = ei2 - q.z;
              a2 = fmaf(q.y, EXP2(-(u * u)), a2); a2 = fmaf(q.w, EXP2(-(v * v)), a2); }
            { float u = ei3 - q.x, v = ei3 - q.z;
              a3 = fmaf(q.y, EXP2(-(u * u)), a3); a3 = fmaf(q.w, EXP2(-(v * v)), a3); }
        }
    }
    __syncthreads();
    sredf[wv * 256 +       lane] = a0;
    sredf[wv * 256 +  64 + lane] = a1;
    sredf[wv * 256 + 128 + lane] = a2;
    sredf[wv * 256 + 192 + lane] = a3;
    __syncthreads();
    partial[y * nmax + ib * 256 + t] =
        sredf[t] + sredf[256 + t] + sredf[512 + t] + sredf[768 + t];
}

__global__ __launch_bounds__(BLK) void fin_k(const float* __restrict__ partial,
                                             float* __restrict__ out, int n, int nmax) {
    int i = blockIdx.x * BLK + threadIdx.x;
    if (i < n) {
        float p = 0.f;
        #pragma unroll
        for (int y = 0; y < YWK; ++y) p += partial[y * nmax + i];
        out[i] = logf(p + 1e-10f);
    }
}

extern "C" void kernel_launch(void* const* d_in, const int* in_sizes, int n_in,
                              void* d_out, int out_size, void* d_ws, size_t ws_size,
                              hipStream_t stream) {
    const float* d = (const float*)d_in[0];
    const float* w = (const float*)d_in[1];
    float* out = (float*)d_out;
    const int n = in_sizes[0];

    const int nmax = ((n + 255) / 256) * 256;   // 12032
    const int IB = nmax / 256;                  // 47
    const int WIN = nmax / YWK;                 // 376

    // ws layout (float units): ejwj float2[nmax] | partial float[YWK*nmax]
    float*  wsf     = (float*)d_ws;
    float2* ejwj    = (float2*)wsf;
    float*  partial = wsf + 2 * nmax;

    sel_k<<<1, 1024, 0, stream>>>(d, w, ejwj, n, nmax);
    dim3 grid(IB, YWK);
    kde_k<<<grid, BLK, 0, stream>>>(ejwj, partial, n, nmax, WIN);
    fin_k<<<IB, BLK, 0, stream>>>(partial, out, n, nmax);
}